// Round 11
// baseline (108.203 us; speedup 1.0000x reference)
//
#include <hip/hip_runtime.h>
#include <hip/hip_bf16.h>
#include <math.h>

// Problem constants
constexpr int B = 4, S = 4096, N = 16, D = 64, M = 4;
constexpr int SND = S * N * D;      // b stride for q/k/v (floats)
constexpr int ND  = N * D;          // s stride (floats)
constexpr int DD  = D * D;          // 4096
constexpr int NCH = 32;             // k1 chunks per bn
constexpr int SPB = S / NCH;        // 128 s per block (4 stages of 32)

typedef __attribute__((ext_vector_type(8))) short bf16x8;
typedef __attribute__((ext_vector_type(4))) float f32x4;
typedef unsigned short u16;
typedef unsigned int u32;

__device__ inline u16 f2bf(float x) {
  __hip_bfloat16 h = __float2bfloat16(x);   // RNE
  return __builtin_bit_cast(u16, h);
}

// ---------------------------------------------------------------------------
// PROBE 0: pure read of k,v in k1's exact geometry (256B n-slice per 4KB row).
// No LDS, no barriers, 16 independent dwordx4 per thread, no reg cap.
// grid = (64, 32), block = 256. Answers: what can this GEOMETRY stream?
// ---------------------------------------------------------------------------
__global__ __launch_bounds__(256) void probe_sliced(const float* __restrict__ kg,
                                                    const float* __restrict__ vg,
                                                    float* __restrict__ sink) {
  const int t = threadIdx.x;
  const int bn = blockIdx.x, ch = blockIdx.y;
  const int b = bn >> 4, n = bn & 15;
  const int rp = t >> 4, c = t & 15;
  const size_t base = (size_t)b * SND + (size_t)n * D + (size_t)ch * SPB * ND;

  float s0 = 0.f, s1 = 0.f, s2 = 0.f, s3 = 0.f;
#pragma unroll
  for (int st = 0; st < 4; ++st) {
    const float* kp = kg + base + (size_t)(st * 32 + 2 * rp) * ND + 4 * c;
    const float* vp = vg + base + (size_t)(st * 32 + 2 * rp) * ND + 4 * c;
    const float4 a  = *(const float4*)kp;
    const float4 b4 = *(const float4*)(kp + ND);
    const float4 cc = *(const float4*)vp;
    const float4 d4 = *(const float4*)(vp + ND);
    s0 += a.x + a.y + a.z + a.w;
    s1 += b4.x + b4.y + b4.z + b4.w;
    s2 += cc.x + cc.y + cc.z + cc.w;
    s3 += d4.x + d4.y + d4.z + d4.w;
  }
  sink[((size_t)blockIdx.y * 64 + blockIdx.x) * 256 + t] = s0 + s1 + s2 + s3;
}

// ---------------------------------------------------------------------------
// PROBE 1: pure read of k,v fully LINEAR (block = contiguous 32KB of each).
// grid = 2048, block = 256. Answers: geometry-free streaming ceiling.
// ---------------------------------------------------------------------------
__global__ __launch_bounds__(256) void probe_linear(const float* __restrict__ kg,
                                                    const float* __restrict__ vg,
                                                    float* __restrict__ sink) {
  const int t = threadIdx.x;
  const size_t base = (size_t)blockIdx.x * 8192;   // 2048 blocks x 8192 floats
  float s = 0.f;
#pragma unroll
  for (int i = 0; i < 8; ++i) {
    const float4 a = *(const float4*)(kg + base + (size_t)(i * 256 + t) * 4);
    const float4 b = *(const float4*)(vg + base + (size_t)(i * 256 + t) * 4);
    s += a.x + a.y + a.z + a.w + b.x + b.y + b.z + b.w;
  }
  sink[(size_t)blockIdx.x * 256 + t] = s;
}

// ---------------------------------------------------------------------------
// Kernel 1: part[bn][ch] = sum_{s in chunk} K[s,:]^T ⊗ V[s,:]  via MFMA (bf16).
// Round-10 structure with the VGPR handcuff REMOVED (no min-wave bound):
// 16 KB LDS double-buffer, 16-VGPR acc strip per wave, 4 dwordx4/thread/stage.
// grid = (64 bn, 32 ch), block = 256 (4 waves).
// ---------------------------------------------------------------------------
__global__ __launch_bounds__(256) void k1_partials(const float* __restrict__ kg,
                                                   const float* __restrict__ vg,
                                                   u16* __restrict__ part) {
  __shared__ u16 kT[2][64][32];
  __shared__ u16 vT[2][64][32];

  const int t = threadIdx.x, w = t >> 6, l = t & 63;
  const int lr = l & 15, lg = l >> 4;       // mfma lane coords
  const int rp = 4 * w + (l >> 4);          // staging row-pair 0..15
  const int c  = l & 15;                    // staging d-chunk (4 floats)
  const int bn = blockIdx.x;
  const int b = bn >> 4, n = bn & 15;
  const int ch = blockIdx.y;

  const size_t base = (size_t)b * SND + (size_t)n * D + (size_t)ch * SPB * ND;

  f32x4 acc[4];
#pragma unroll
  for (int i = 0; i < 4; ++i) acc[i] = (f32x4)0.f;

  float kr[2][2][4], vr[2][2][4];           // [reg-set][row-of-pair][4 floats]

#define K1_LOAD(st, sb)                                                     \
  {                                                                         \
    const float* kp = kg + base + (size_t)((st) * 32 + 2 * rp) * ND + 4 * c;\
    const float* vp = vg + base + (size_t)((st) * 32 + 2 * rp) * ND + 4 * c;\
    *(float4*)kr[sb][0] = *(const float4*)kp;                               \
    *(float4*)kr[sb][1] = *(const float4*)(kp + ND);                        \
    *(float4*)vr[sb][0] = *(const float4*)vp;                               \
    *(float4*)vr[sb][1] = *(const float4*)(vp + ND);                        \
  }

#define K1_WRITE(buf, sb)                                                   \
  {                                                                         \
    const int sl = 2 * rp;                                                  \
    _Pragma("unroll") for (int o = 0; o < 4; ++o) {                         \
      const int d = 4 * c + o;                                              \
      const int slot = (((sl >> 3) ^ ((d >> 2) & 3)) << 3) + (sl & 7);      \
      *(u32*)&kT[buf][d][slot] =                                            \
          (u32)f2bf(kr[sb][0][o]) | ((u32)f2bf(kr[sb][1][o]) << 16);        \
      *(u32*)&vT[buf][d][slot] =                                            \
          (u32)f2bf(vr[sb][0][o]) | ((u32)f2bf(vr[sb][1][o]) << 16);        \
    }                                                                       \
  }

#define K1_COMPUTE(buf)                                                     \
  {                                                                         \
    const int grp = (lg ^ (lr >> 2)) << 3;                                  \
    bf16x8 af = *(const bf16x8*)&kT[buf][16 * w + lr][grp];                 \
    bf16x8 bq[4];                                                           \
    _Pragma("unroll") for (int ni = 0; ni < 4; ++ni)                        \
      bq[ni] = *(const bf16x8*)&vT[buf][16 * ni + lr][grp];                 \
    _Pragma("unroll") for (int ni = 0; ni < 4; ++ni)                        \
      acc[ni] = __builtin_amdgcn_mfma_f32_16x16x32_bf16(af, bq[ni],         \
                                                        acc[ni], 0, 0, 0);  \
  }

  // prologue
  K1_LOAD(0, 0);
  K1_WRITE(0, 0);
  K1_LOAD(1, 1);
  __syncthreads();

  // 4 stages of 32 s; one barrier per stage; writes go to the other buffer
#pragma unroll
  for (int st = 0; st < 4; ++st) {
    K1_COMPUTE(st & 1);
    if (st < 3) K1_WRITE((st + 1) & 1, (st + 1) & 1);
    if (st < 2) K1_LOAD(st + 2, st & 1);
    if (st < 3) __syncthreads();
  }

#undef K1_LOAD
#undef K1_WRITE
#undef K1_COMPUTE

  // bf16 partial store: wave w owns C rows 16w..16w+15 (r6-verified mapping)
  u16* p = part + ((size_t)bn * NCH + ch) * DD;
#pragma unroll
  for (int ni = 0; ni < 4; ++ni)
#pragma unroll
    for (int ri = 0; ri < 4; ++ri)
      p[(16 * w + 4 * lg + ri) * 64 + 16 * ni + lr] = f2bf(acc[ni][ri]);
}

// ---------------------------------------------------------------------------
// Kernel 2: Meff combine (part is bf16). Emits bf16 TRANSPOSED meffT[bn][v][k].
// grid = (64, 16), block = 256.
// ---------------------------------------------------------------------------
__global__ __launch_bounds__(256) void k2_combine(const u16* __restrict__ part,
                                                  const float* __restrict__ memg,
                                                  const float* __restrict__ decay,
                                                  const float* __restrict__ gatew,
                                                  u16* __restrict__ meffT) {
  const int t = threadIdx.x;
  const int bn = blockIdx.x;
  const int b = bn >> 4, n = bn & 15;
  const int kv = blockIdx.y * 256 + t;
  const int k = kv >> 6, v = kv & 63;

  float gw[M], df[M];
#pragma unroll
  for (int m = 0; m < M; ++m) { gw[m] = gatew[m]; df[m] = decay[m]; }
  const float mx = fmaxf(fmaxf(gw[0], gw[1]), fmaxf(gw[2], gw[3]));
  float e[M], esum = 0.f;
#pragma unroll
  for (int m = 0; m < M; ++m) { e[m] = expf(gw[m] - mx); esum += e[m]; }
  float wgt[M], cc = 0.f;
#pragma unroll
  for (int m = 0; m < M; ++m) {
    const float g = e[m] / esum;
    const float sg = 1.f / (1.f + expf(-df[m]));
    wgt[m] = g * sg;
    cc += g * (1.f - sg);
  }

  const u16* pb = part + (size_t)bn * NCH * DD + kv;
  float ni = 0.f;
#pragma unroll 8
  for (int ch = 0; ch < NCH; ++ch) {
    __hip_bfloat16 h = __builtin_bit_cast(__hip_bfloat16, pb[(size_t)ch * DD]);
    ni += __bfloat162float(h);
  }
  float a = cc * ni;
#pragma unroll
  for (int m = 0; m < M; ++m)
    a += wgt[m] * memg[(((size_t)b * M + m) * N + n) * DD + kv];

  meffT[(size_t)bn * DD + v * 64 + k] = f2bf(a);
}

// ---------------------------------------------------------------------------
// Kernel 3: out[s,v] = q[s,:] @ Meff  via MFMA, LDS-free, free-running.
// grid = (64 bn, 16), block = 256 (4 waves); wave handles 64 s-rows x 64 v.
// ---------------------------------------------------------------------------
__global__ __launch_bounds__(256, 4) void k3_out(const float* __restrict__ qg,
                                                 const u16* __restrict__ meffT,
                                                 float* __restrict__ outg) {
  const int t = threadIdx.x, w = t >> 6, l = t & 63;
  const int lr = l & 15, lg = l >> 4;
  const int bn = blockIdx.x;
  const int b = bn >> 4, n = bn & 15;
  const int s0 = blockIdx.y * 256 + w * 64;

  const u16* mb = meffT + (size_t)bn * DD;
  bf16x8 bfr[4][2];
#pragma unroll
  for (int ni = 0; ni < 4; ++ni)
#pragma unroll
    for (int ks = 0; ks < 2; ++ks)
      bfr[ni][ks] = *(const bf16x8*)(mb + (16 * ni + lr) * 64 + 32 * ks + 8 * lg);

  f32x4 acc[4][4];
#pragma unroll
  for (int i = 0; i < 4; ++i)
#pragma unroll
    for (int j = 0; j < 4; ++j) acc[i][j] = (f32x4)0.f;

  const size_t qbase = (size_t)b * SND + (size_t)n * D;

#pragma unroll
  for (int mi = 0; mi < 4; ++mi) {
    const float* qr = qg + qbase + (size_t)(s0 + 16 * mi + lr) * ND + 8 * lg;
#pragma unroll
    for (int ks = 0; ks < 2; ++ks) {
      float qa[8];
      *(float4*)&qa[0] = *(const float4*)(qr + 32 * ks);
      *(float4*)&qa[4] = *(const float4*)(qr + 32 * ks + 4);
      bf16x8 a;
#pragma unroll
      for (int j = 0; j < 8; ++j) a[j] = (short)f2bf(qa[j]);
#pragma unroll
      for (int ni = 0; ni < 4; ++ni)
        acc[mi][ni] = __builtin_amdgcn_mfma_f32_16x16x32_bf16(a, bfr[ni][ks],
                                                              acc[mi][ni], 0, 0, 0);
    }
  }

#pragma unroll
  for (int mi = 0; mi < 4; ++mi)
#pragma unroll
    for (int ni = 0; ni < 4; ++ni)
#pragma unroll
      for (int ri = 0; ri < 4; ++ri)
        outg[qbase + (size_t)(s0 + 16 * mi + 4 * lg + ri) * ND + 16 * ni + lr] =
            acc[mi][ni][ri];
}

// ---------------------------------------------------------------------------
extern "C" void kernel_launch(void* const* d_in, const int* in_sizes, int n_in,
                              void* d_out, int out_size, void* d_ws, size_t ws_size,
                              hipStream_t stream) {
  const float* q     = (const float*)d_in[0];
  const float* k     = (const float*)d_in[1];
  const float* v     = (const float*)d_in[2];
  const float* memg  = (const float*)d_in[3];
  const float* decay = (const float*)d_in[4];
  const float* gatew = (const float*)d_in[5];
  float* out = (float*)d_out;

  // ws layout: [meffT 512KB][part 16MB][sink0 2MB][sink1 2MB]  (~21.3 MB)
  u16* meffT = (u16*)d_ws;
  const size_t meffT_bytes = (size_t)64 * DD * sizeof(u16);
  u16* part = (u16*)((char*)d_ws + meffT_bytes);
  const size_t part_bytes = (size_t)64 * NCH * DD * sizeof(u16);
  float* sink0 = (float*)((char*)d_ws + meffT_bytes + part_bytes);
  float* sink1 = sink0 + (size_t)2048 * 256;

  // real pipeline first
  hipLaunchKernelGGL(k1_partials, dim3(64, NCH), dim3(256), 0, stream,
                     k, v, part);
  hipLaunchKernelGGL(k2_combine, dim3(64, 16), dim3(256), 0, stream,
                     part, memg, decay, gatew, meffT);
  hipLaunchKernelGGL(k3_out, dim3(64, 16), dim3(256), 0, stream,
                     q, meffT, out);

  // instrumentation probes (read-only on inputs; results to ws sinks)
  hipLaunchKernelGGL(probe_sliced, dim3(64, 32), dim3(256), 0, stream,
                     k, v, sink0);
  hipLaunchKernelGGL(probe_linear, dim3(2048), dim3(256), 0, stream,
                     k, v, sink1);
}

// Round 12
// 66.415 us; speedup vs baseline: 1.6292x; 1.6292x over previous
//
#include <hip/hip_runtime.h>
#include <hip/hip_bf16.h>
#include <math.h>

// Problem constants
constexpr int B = 4, S = 4096, N = 16, D = 64, M = 4;
constexpr int SND = S * N * D;      // b stride for q/k/v (floats)
constexpr int ND  = N * D;          // s stride (floats)
constexpr int DD  = D * D;          // 4096
constexpr int NCH = 32;             // k1 chunks per bn
constexpr int SPB = S / NCH;        // 128 s per block

typedef __attribute__((ext_vector_type(8))) short bf16x8;
typedef __attribute__((ext_vector_type(4))) float f32x4;
typedef unsigned short u16;
typedef unsigned int u32;

__device__ inline u16 f2bf(float x) {
  __hip_bfloat16 h = __float2bfloat16(x);   // RNE
  return __builtin_bit_cast(u16, h);
}

// ---------------------------------------------------------------------------
// Kernel 1: part[bn][ch] = sum_{s in chunk} K[s,:]^T ⊗ V[s,:]  via MFMA (bf16).
// PROBE-SHAPED (r11 evidence: this exact read geometry streams 6.5 TB/s when
// 16 independent dwordx4 are issued back-to-back):
//   phase 1: issue ALL 16 loads (whole 128-s chunk) into 64 data VGPRs
//   phase 2: convert+ds_write as loads land (compiler emits counted vmcnt)
//   phase 3: ONE __syncthreads
//   phase 4: 16 MFMA per wave from a single 32 KB swizzled LDS image
// LDS swizzle: element (d,s) octet-slot g = (s>>3) ^ (d&15)  ->
//   fragment ds_read_b128 lanes lr / lr^8 share a bank pair = 2-way = free;
//   staging writes <=4-way. Frag & C mapping identical to r6/r10 verified path.
// grid = (64 bn, 32 ch), block = 256 (4 waves). No launch_bounds reg cap.
// ---------------------------------------------------------------------------
__global__ __launch_bounds__(256) void k1_partials(const float* __restrict__ kg,
                                                   const float* __restrict__ vg,
                                                   u16* __restrict__ part) {
  __shared__ u16 kT[64][128];       // [d][swizzled s-slot]
  __shared__ u16 vT[64][128];

  const int t = threadIdx.x, w = t >> 6, l = t & 63;
  const int lr = l & 15, lg = l >> 4;   // mfma lane coords
  const int rp = t >> 4;                // staging row-pair 0..15
  const int c  = t & 15;                // staging d-chunk (4 floats)
  const int bn = blockIdx.x, ch = blockIdx.y;
  const int b = bn >> 4, n = bn & 15;

  const size_t base = (size_t)b * SND + (size_t)n * D + (size_t)ch * SPB * ND;

  // ---- phase 1: issue all 16 independent dwordx4 loads ----
  float4 kr[8], vr[8];                  // [stage*2 + row-of-pair]
#pragma unroll
  for (int st = 0; st < 4; ++st) {
    const float* kp = kg + base + (size_t)(st * 32 + 2 * rp) * ND + 4 * c;
    const float* vp = vg + base + (size_t)(st * 32 + 2 * rp) * ND + 4 * c;
    kr[2 * st]     = *(const float4*)kp;
    kr[2 * st + 1] = *(const float4*)(kp + ND);
    vr[2 * st]     = *(const float4*)vp;
    vr[2 * st + 1] = *(const float4*)(vp + ND);
  }

  // ---- phase 2: convert + swizzled LDS write ----
#pragma unroll
  for (int st = 0; st < 4; ++st) {
    const int s  = st * 32 + 2 * rp;    // even
    const int so = s >> 3, sl = s & 7;
    const float* k0 = (const float*)&kr[2 * st];
    const float* k1 = (const float*)&kr[2 * st + 1];
    const float* v0 = (const float*)&vr[2 * st];
    const float* v1 = (const float*)&vr[2 * st + 1];
#pragma unroll
    for (int o = 0; o < 4; ++o) {
      const int d = 4 * c + o;
      const int slot = ((so ^ (d & 15)) << 3) + sl;
      *(u32*)&kT[d][slot] = (u32)f2bf(k0[o]) | ((u32)f2bf(k1[o]) << 16);
      *(u32*)&vT[d][slot] = (u32)f2bf(v0[o]) | ((u32)f2bf(v1[o]) << 16);
    }
  }

  __syncthreads();                      // the ONLY barrier

  // ---- phase 4: 4 K=32 steps, wave w owns C rows 16w..16w+15 ----
  f32x4 acc[4];
#pragma unroll
  for (int i = 0; i < 4; ++i) acc[i] = (f32x4)0.f;

#pragma unroll
  for (int kk = 0; kk < 4; ++kk) {
    const int so = 4 * kk + lg;         // s-octet: s = 32*kk + 8*lg + j
    const int da = 16 * w + lr;
    bf16x8 af = *(const bf16x8*)&kT[da][(so ^ (da & 15)) << 3];
    bf16x8 bq[4];
#pragma unroll
    for (int ni = 0; ni < 4; ++ni) {
      const int db = 16 * ni + lr;
      bq[ni] = *(const bf16x8*)&vT[db][(so ^ (db & 15)) << 3];
    }
#pragma unroll
    for (int ni = 0; ni < 4; ++ni)
      acc[ni] = __builtin_amdgcn_mfma_f32_16x16x32_bf16(af, bq[ni],
                                                        acc[ni], 0, 0, 0);
  }

  // ---- store bf16 partial (r6/r10-verified C mapping) ----
  u16* p = part + ((size_t)bn * NCH + ch) * DD;
#pragma unroll
  for (int ni = 0; ni < 4; ++ni)
#pragma unroll
    for (int ri = 0; ri < 4; ++ri)
      p[(16 * w + 4 * lg + ri) * 64 + 16 * ni + lr] = f2bf(acc[ni][ri]);
}

// ---------------------------------------------------------------------------
// Kernel 2: Meff combine (part is bf16). Emits bf16 TRANSPOSED meffT[bn][v][k].
// grid = (64, 16), block = 256.
// ---------------------------------------------------------------------------
__global__ __launch_bounds__(256) void k2_combine(const u16* __restrict__ part,
                                                  const float* __restrict__ memg,
                                                  const float* __restrict__ decay,
                                                  const float* __restrict__ gatew,
                                                  u16* __restrict__ meffT) {
  const int t = threadIdx.x;
  const int bn = blockIdx.x;
  const int b = bn >> 4, n = bn & 15;
  const int kv = blockIdx.y * 256 + t;
  const int k = kv >> 6, v = kv & 63;

  float gw[M], df[M];
#pragma unroll
  for (int m = 0; m < M; ++m) { gw[m] = gatew[m]; df[m] = decay[m]; }
  const float mx = fmaxf(fmaxf(gw[0], gw[1]), fmaxf(gw[2], gw[3]));
  float e[M], esum = 0.f;
#pragma unroll
  for (int m = 0; m < M; ++m) { e[m] = expf(gw[m] - mx); esum += e[m]; }
  float wgt[M], cc = 0.f;
#pragma unroll
  for (int m = 0; m < M; ++m) {
    const float g = e[m] / esum;
    const float sg = 1.f / (1.f + expf(-df[m]));
    wgt[m] = g * sg;
    cc += g * (1.f - sg);
  }

  const u16* pb = part + (size_t)bn * NCH * DD + kv;
  float ni = 0.f;
#pragma unroll 8
  for (int ch = 0; ch < NCH; ++ch) {
    __hip_bfloat16 h = __builtin_bit_cast(__hip_bfloat16, pb[(size_t)ch * DD]);
    ni += __bfloat162float(h);
  }
  float a = cc * ni;
#pragma unroll
  for (int m = 0; m < M; ++m)
    a += wgt[m] * memg[(((size_t)b * M + m) * N + n) * DD + kv];

  meffT[(size_t)bn * DD + v * 64 + k] = f2bf(a);
}

// ---------------------------------------------------------------------------
// Kernel 3: out[s,v] = q[s,:] @ Meff  via MFMA, LDS-free, free-running.
// grid = (64 bn, 16), block = 256 (4 waves); wave handles 64 s-rows x 64 v.
// ---------------------------------------------------------------------------
__global__ __launch_bounds__(256, 4) void k3_out(const float* __restrict__ qg,
                                                 const u16* __restrict__ meffT,
                                                 float* __restrict__ outg) {
  const int t = threadIdx.x, w = t >> 6, l = t & 63;
  const int lr = l & 15, lg = l >> 4;
  const int bn = blockIdx.x;
  const int b = bn >> 4, n = bn & 15;
  const int s0 = blockIdx.y * 256 + w * 64;

  const u16* mb = meffT + (size_t)bn * DD;
  bf16x8 bfr[4][2];
#pragma unroll
  for (int ni = 0; ni < 4; ++ni)
#pragma unroll
    for (int ks = 0; ks < 2; ++ks)
      bfr[ni][ks] = *(const bf16x8*)(mb + (16 * ni + lr) * 64 + 32 * ks + 8 * lg);

  f32x4 acc[4][4];
#pragma unroll
  for (int i = 0; i < 4; ++i)
#pragma unroll
    for (int j = 0; j < 4; ++j) acc[i][j] = (f32x4)0.f;

  const size_t qbase = (size_t)b * SND + (size_t)n * D;

#pragma unroll
  for (int mi = 0; mi < 4; ++mi) {
    const float* qr = qg + qbase + (size_t)(s0 + 16 * mi + lr) * ND + 8 * lg;
#pragma unroll
    for (int ks = 0; ks < 2; ++ks) {
      float qa[8];
      *(float4*)&qa[0] = *(const float4*)(qr + 32 * ks);
      *(float4*)&qa[4] = *(const float4*)(qr + 32 * ks + 4);
      bf16x8 a;
#pragma unroll
      for (int j = 0; j < 8; ++j) a[j] = (short)f2bf(qa[j]);
#pragma unroll
      for (int ni = 0; ni < 4; ++ni)
        acc[mi][ni] = __builtin_amdgcn_mfma_f32_16x16x32_bf16(a, bfr[ni][ks],
                                                              acc[mi][ni], 0, 0, 0);
    }
  }

#pragma unroll
  for (int mi = 0; mi < 4; ++mi)
#pragma unroll
    for (int ni = 0; ni < 4; ++ni)
#pragma unroll
      for (int ri = 0; ri < 4; ++ri)
        outg[qbase + (size_t)(s0 + 16 * mi + 4 * lg + ri) * ND + 16 * ni + lr] =
            acc[mi][ni][ri];
}

// ---------------------------------------------------------------------------
extern "C" void kernel_launch(void* const* d_in, const int* in_sizes, int n_in,
                              void* d_out, int out_size, void* d_ws, size_t ws_size,
                              hipStream_t stream) {
  const float* q     = (const float*)d_in[0];
  const float* k     = (const float*)d_in[1];
  const float* v     = (const float*)d_in[2];
  const float* memg  = (const float*)d_in[3];
  const float* decay = (const float*)d_in[4];
  const float* gatew = (const float*)d_in[5];
  float* out = (float*)d_out;

  u16* meffT = (u16*)d_ws;                            // 512 KB
  const size_t meffT_bytes = (size_t)64 * DD * sizeof(u16);
  u16* part = (u16*)((char*)d_ws + meffT_bytes);      // 16 MB bf16 partials

  hipLaunchKernelGGL(k1_partials, dim3(64, NCH), dim3(256), 0, stream,
                     k, v, part);
  hipLaunchKernelGGL(k2_combine, dim3(64, 16), dim3(256), 0, stream,
                     part, memg, decay, gatew, meffT);
  hipLaunchKernelGGL(k3_out, dim3(64, 16), dim3(256), 0, stream,
                     q, meffT, out);
}